// Round 12
// baseline (710.151 us; speedup 1.0000x reference)
//
#include <hip/hip_runtime.h>
#include <math.h>

// Problem constants
#define T_   8
#define K_   64
#define D_   512
#define CIN_ 1536
#define B_   32
#define S_   64    // H*W = 8*8
#define NT_  256   // B*T

// Workspace layout (float offsets)
#define WLO_BF16  786432u     // bf16-element offset of Wlo within bf16 view
#define WXT_OFF   786432u     // [512][64]  transposed w_x (float offset, unused since R12)
#define XT_OFF    819200u     // [256][512][64]
#define WXPB_OFF  9207808u    // [256][64][64]
#define ATTV_OFF  10256384u   // region reused: att_x pack, W2 pack, b2
#define HS_OFF    11436032u   // [8][32][64][64]
#define ASUM_OFF  13041664u   // [32][8][64]
// conv-weight pack (bf16 elements): 5 weights x (hi 36864 + lo 36864),
// layout per weight: [dydx(9)][o(64)][i(64)]. Only hi halves are read (R4).
// Slots: 0=att_h_w 1=share_w 2=U_z 3=U_r 4=U_h.
#define WPB       25034752u
// ATTV-region tenants (all verified inside float span 10256384..11436032):
#define WATTX_BF16 20512768u  // att_x hi pack  (36864 bf16)
#define W2HI_BF16  20549632u  // W2 hi  [64][1536] bf16
#define W2LO_BF16  20647936u  // W2 lo  [64][1536] bf16 (ends 20746240 < 22872064)
#define B2_OFF     11435968u  // b2 [64] floats, abuts HS_OFF exactly

typedef __bf16 v8bf __attribute__((ext_vector_type(8)));
typedef __bf16 v4bf __attribute__((ext_vector_type(4)));
typedef float  v4f  __attribute__((ext_vector_type(4)));
typedef _Float16 v4h __attribute__((ext_vector_type(4)));
typedef _Float16 v8h __attribute__((ext_vector_type(8)));

// ---------------------------------------------------------------------------
// prep: split redu_w -> bf16 hi/lo (w_x transpose no longer needed)
__global__ __launch_bounds__(256) void k_prep(const float* __restrict__ redu_w,
                                              float* __restrict__ ws) {
    unsigned idx = blockIdx.x * 256u + threadIdx.x;
    if (idx < 786432u) {
        float f = redu_w[idx];
        __bf16 h = (__bf16)f;
        __bf16 l = (__bf16)(f - (float)h);
        __bf16* wb = (__bf16*)ws;
        wb[idx] = h;
        wb[WLO_BF16 + idx] = l;
    }
}

// ---------------------------------------------------------------------------
// prep conv weights: [o][i][ky][kx] fp32 -> bf16 hi/lo [dydx][o][i].
// Slots 0..4 as in R8; slot 5 (att_x) hi-only into WATTX (R10).
__global__ __launch_bounds__(256) void k_prep_w(const float* __restrict__ w0,
                                                const float* __restrict__ w1,
                                                const float* __restrict__ w2,
                                                const float* __restrict__ w3,
                                                const float* __restrict__ w4,
                                                const float* __restrict__ w5,
                                                float* __restrict__ ws) {
    unsigned idx = blockIdx.x * 256u + threadIdx.x;
    if (idx >= 221184u) return;
    unsigned w = idx / 36864u, r = idx % 36864u;
    const float* src = (w == 0) ? w0 : (w == 1) ? w1 : (w == 2) ? w2
                     : (w == 3) ? w3 : (w == 4) ? w4 : w5;
    float f = src[r];
    __bf16 h = (__bf16)f;
    __bf16 l = (__bf16)(f - (float)h);
    unsigned o = r / 576u, rem = r % 576u, ii = rem / 9u, dydx = rem % 9u;
    __bf16* wb = (__bf16*)ws;
    if (w < 5u) {
        unsigned dst = WPB + w * 73728u + (dydx * 64u + o) * 64u + ii;
        wb[dst] = h;
        wb[dst + 36864u] = l;
    } else {
        wb[WATTX_BF16 + (dydx * 64u + o) * 64u + ii] = h;   // hi only
    }
}

// ---------------------------------------------------------------------------
// R12: W2 = w_x @ redu_w (64x1536) -> bf16 hi/lo; b2 = w_x @ redu_b.
// One block per k-row. redu_w column reads are coalesced across threads and
// L2-resident (3.1 MB); 6 independent accumulators per thread for MLP.
__global__ __launch_bounds__(256) void k_w2(const float* __restrict__ w_x,
                                            const float* __restrict__ redu_w,
                                            const float* __restrict__ redu_b,
                                            float* __restrict__ ws) {
    __shared__ float wrow[512];
    __shared__ float red[256];
    const int k = blockIdx.x;
    const int tid = threadIdx.x;
    wrow[tid] = w_x[k * 512 + tid];
    wrow[tid + 256] = w_x[k * 512 + tid + 256];
    __syncthreads();
    float acc[6] = {0.f, 0.f, 0.f, 0.f, 0.f, 0.f};
    for (int d = 0; d < 512; ++d) {
        float w = wrow[d];
        const float* rr = &redu_w[d * 1536 + tid];
#pragma unroll
        for (int j = 0; j < 6; ++j) acc[j] = fmaf(w, rr[j * 256], acc[j]);
    }
    __bf16* wb = (__bf16*)ws;
#pragma unroll
    for (int j = 0; j < 6; ++j) {
        int c = tid + j * 256;
        __bf16 h = (__bf16)acc[j];
        __bf16 l = (__bf16)(acc[j] - (float)h);
        wb[W2HI_BF16 + k * 1536 + c] = h;
        wb[W2LO_BF16 + k * 1536 + c] = l;
    }
    float p = wrow[tid] * redu_b[tid] + wrow[tid + 256] * redu_b[tid + 256];
    red[tid] = p;
    __syncthreads();
    for (int off = 128; off > 0; off >>= 1) {
        if (tid < off) red[tid] += red[tid + off];
        __syncthreads();
    }
    if (tid == 0) ws[B2_OFF + k] = red[0];
}

// ---------------------------------------------------------------------------
// R12: wxpb[n] = W2 @ x[n] + b2 via hi/lo 3-product MFMA (K=1536).
// Replaces the old two-stage (xt -> wxpb) dependency so the recurrence can
// launch without waiting for the big xt GEMM. Structure mirrors k_gemm_xt's
// staging; each wave owns 16 output rows (M=64 total).
__global__ __launch_bounds__(256) void k_wxpb_direct(const float* __restrict__ x,
                                                     float* __restrict__ ws) {
    __shared__ __bf16 xhi_s[64 * 72];
    __shared__ __bf16 xlo_s[64 * 72];
    const __bf16* __restrict__ W2h = (const __bf16*)ws + W2HI_BF16;
    const __bf16* __restrict__ W2l = (const __bf16*)ws + W2LO_BF16;
    float* wxpb = ws + WXPB_OFF;
    const int n = blockIdx.x;
    const int tid = threadIdx.x;
    const int wave = tid >> 6, lane = tid & 63;
    const int lrow = lane & 15, lkg = lane >> 4;
    const float* __restrict__ xn = x + n * 98304;
    const int s4 = tid & 15, cb = tid >> 4;

    v4f acc[4];
#pragma unroll
    for (int nt = 0; nt < 4; ++nt) acc[nt] = (v4f){0.f, 0.f, 0.f, 0.f};

    for (int c0 = 0; c0 < 1536; c0 += 64) {
        float4 v[4];
#pragma unroll
        for (int j = 0; j < 4; ++j)
            v[j] = *(const float4*)&xn[(c0 + cb * 4 + j) * 64 + s4 * 4];
        __syncthreads();
#pragma unroll
        for (int i = 0; i < 4; ++i) {
            v4bf hv, lv;
#pragma unroll
            for (int j = 0; j < 4; ++j) {
                float f = ((const float*)&v[j])[i];
                __bf16 h = (__bf16)f;
                hv[j] = h;
                lv[j] = (__bf16)(f - (float)h);
            }
            int row = s4 * 4 + i;
            *(v4bf*)&xhi_s[row * 72 + cb * 4] = hv;
            *(v4bf*)&xlo_s[row * 72 + cb * 4] = lv;
        }
        __syncthreads();
#pragma unroll
        for (int ks = 0; ks < 64; ks += 32) {
            v8bf bh[4], bl[4];
#pragma unroll
            for (int nt = 0; nt < 4; ++nt) {
                int off = (nt * 16 + lrow) * 72 + ks + lkg * 8;
                bh[nt] = *(const v8bf*)&xhi_s[off];
                bl[nt] = *(const v8bf*)&xlo_s[off];
            }
            int gi = (wave * 16 + lrow) * 1536 + c0 + ks + lkg * 8;
            v8bf ah = *(const v8bf*)&W2h[gi];
            v8bf al = *(const v8bf*)&W2l[gi];
#pragma unroll
            for (int nt = 0; nt < 4; ++nt) {
                acc[nt] = __builtin_amdgcn_mfma_f32_16x16x32_bf16(ah, bh[nt], acc[nt], 0, 0, 0);
                acc[nt] = __builtin_amdgcn_mfma_f32_16x16x32_bf16(ah, bl[nt], acc[nt], 0, 0, 0);
                acc[nt] = __builtin_amdgcn_mfma_f32_16x16x32_bf16(al, bh[nt], acc[nt], 0, 0, 0);
            }
        }
    }
#pragma unroll
    for (int r = 0; r < 4; ++r) {
        int m = wave * 16 + lkg * 4 + r;
        float bias = ws[B2_OFF + m];
#pragma unroll
        for (int nt = 0; nt < 4; ++nt)
            wxpb[(n * 64 + m) * 64 + nt * 16 + lrow] = acc[nt][r] + bias;
    }
}

// ---------------------------------------------------------------------------
// R8 conv: 4 waves, each wave owns rows mt*16..+15, all 64 cols (acc[4]).
__device__ __forceinline__ void conv_mfma(const __bf16* __restrict__ Wh,
                                          const __bf16* tS,
                                          int l15, int kg8, int mt, v4f acc[4]) {
    v8bf vz;
#pragma unroll
    for (int q = 0; q < 8; ++q) vz[q] = (__bf16)0.f;
#pragma unroll
    for (int i = 0; i < 4; ++i) acc[i] = (v4f){0.f, 0.f, 0.f, 0.f};
    const int yb = l15 >> 3, xb = l15 & 7;
    v8bf wh[9][2];
#pragma unroll
    for (int p = 0; p < 9; ++p) {
        const int wrow = (p * 64 + mt * 16 + l15) * 64 + kg8;
#pragma unroll
        for (int kci = 0; kci < 2; ++kci)
            wh[p][kci] = *(const v8bf*)&Wh[wrow + kci * 32];
    }
#pragma unroll
    for (int dy = 0; dy < 3; ++dy)
#pragma unroll
        for (int dx = 0; dx < 3; ++dx) {
            const int x0 = xb + dx - 1;
            const bool okx = (unsigned)x0 < 8u;
#pragma unroll
            for (int i = 0; i < 4; ++i) {
                const int y0 = yb + dy - 1 + 2 * i;
                const bool ok = ((unsigned)y0 < 8u) & okx;
                const int s0 = ((y0 * 8 + x0) & 63) * 72 + kg8;
#pragma unroll
                for (int kci = 0; kci < 2; ++kci) {
                    v8bf b = ok ? *(const v8bf*)&tS[s0 + kci * 32] : vz;
                    acc[i] = __builtin_amdgcn_mfma_f32_16x16x32_bf16(
                        wh[dy * 3 + dx][kci], b, acc[i], 0, 0, 0);
                }
            }
        }
}

// Fused triple conv over the same tA (ah/Uz/Ur).
__device__ __forceinline__ void conv_mfma3(const __bf16* __restrict__ W0,
                                           const __bf16* __restrict__ W1,
                                           const __bf16* __restrict__ W2,
                                           const __bf16* tS,
                                           int l15, int kg8, int mt,
                                           v4f a0[4], v4f a1[4], v4f a2[4]) {
    v8bf vz;
#pragma unroll
    for (int q = 0; q < 8; ++q) vz[q] = (__bf16)0.f;
#pragma unroll
    for (int i = 0; i < 4; ++i) {
        a0[i] = (v4f){0.f, 0.f, 0.f, 0.f};
        a1[i] = (v4f){0.f, 0.f, 0.f, 0.f};
        a2[i] = (v4f){0.f, 0.f, 0.f, 0.f};
    }
    const int yb = l15 >> 3, xb = l15 & 7;
#pragma unroll
    for (int dy = 0; dy < 3; ++dy) {
        v8bf w0[3][2], w1[3][2], w2[3][2];
#pragma unroll
        for (int dx = 0; dx < 3; ++dx) {
            const int wrow = ((dy * 3 + dx) * 64 + mt * 16 + l15) * 64 + kg8;
#pragma unroll
            for (int kci = 0; kci < 2; ++kci) {
                w0[dx][kci] = *(const v8bf*)&W0[wrow + kci * 32];
                w1[dx][kci] = *(const v8bf*)&W1[wrow + kci * 32];
                w2[dx][kci] = *(const v8bf*)&W2[wrow + kci * 32];
            }
        }
#pragma unroll
        for (int dx = 0; dx < 3; ++dx) {
            const int x0 = xb + dx - 1;
            const bool okx = (unsigned)x0 < 8u;
#pragma unroll
            for (int i = 0; i < 4; ++i) {
                const int y0 = yb + dy - 1 + 2 * i;
                const bool ok = ((unsigned)y0 < 8u) & okx;
                const int s0 = ((y0 * 8 + x0) & 63) * 72 + kg8;
#pragma unroll
                for (int kci = 0; kci < 2; ++kci) {
                    v8bf b = ok ? *(const v8bf*)&tS[s0 + kci * 32] : vz;
                    a0[i] = __builtin_amdgcn_mfma_f32_16x16x32_bf16(w0[dx][kci], b, a0[i], 0, 0, 0);
                    a1[i] = __builtin_amdgcn_mfma_f32_16x16x32_bf16(w1[dx][kci], b, a1[i], 0, 0, 0);
                    a2[i] = __builtin_amdgcn_mfma_f32_16x16x32_bf16(w2[dx][kci], b, a2[i], 0, 0, 0);
                }
            }
        }
    }
}

// ---------------------------------------------------------------------------
// R12 fused kernel: grid 544, 256 threads.
//   blocks 0..31   : the R11 recurrence (reads wxpb, writes hsg/asg) — 371 us
//                    on 32 CUs.
//   blocks 32..543 : the xt GEMM (reads x + redu_w hi/lo, writes xt) — runs
//                    CONCURRENTLY on the 224 idle CUs (no data dependence:
//                    xt is consumed only by k_vlad, after this dispatch).
// Gemm path aliases its 18 KB staging into attv_s so LDS stays 126 KB.
__global__ __launch_bounds__(256) void k_fused(const float* __restrict__ att_b,
                                               const float* __restrict__ share_b,
                                               const float* __restrict__ fc1_w,
                                               const float* __restrict__ fc2_w,
                                               const float* __restrict__ x,
                                               const float* __restrict__ redu_b,
                                               float* __restrict__ ws) {
    __shared__ float h_s[4096];                                   // h [k][s]
    __shared__ __attribute__((aligned(16))) __bf16 tA[64 * 72];   // T(in) [s][kp]
    __shared__ float cA[64 * 65];                                 // conv out / scratch
    __shared__ float cB[64 * 65];
    __shared__ float misc[1088];
    __shared__ __attribute__((aligned(16))) _Float16 attv_s[32768];  // [tp][k][s] fp16
    const int tid = threadIdx.x;

    if (blockIdx.x >= 32) {
        // ================= xt GEMM path =================
        const int gb = blockIdx.x - 32;
        const int n = gb >> 1;
        const int d0 = (gb & 1) * 256;
        const __bf16* __restrict__ Whi = (const __bf16*)ws;
        const __bf16* __restrict__ Wlo = ((const __bf16*)ws) + WLO_BF16;
        float* xt = ws + XT_OFF;
        const int wave = tid >> 6, lane = tid & 63;
        const int lrow = lane & 15, lkg = lane >> 4;
        const int m_base = d0 + wave * 64;
        const float* __restrict__ xn = x + n * 98304;
        const int s4 = tid & 15, cb = tid >> 4;
        __bf16* gxhi = (__bf16*)attv_s;        // alias: 2*4608 bf16 = 18.4 KB
        __bf16* gxlo = gxhi + 4608;

        v4f acc[4][4];
#pragma unroll
        for (int mt = 0; mt < 4; ++mt)
#pragma unroll
            for (int nt = 0; nt < 4; ++nt) acc[mt][nt] = (v4f){0.f, 0.f, 0.f, 0.f};

        for (int c0 = 0; c0 < 1536; c0 += 64) {
            float4 v[4];
#pragma unroll
            for (int j = 0; j < 4; ++j)
                v[j] = *(const float4*)&xn[(c0 + cb * 4 + j) * 64 + s4 * 4];
            __syncthreads();
#pragma unroll
            for (int i = 0; i < 4; ++i) {
                v4bf hv, lv;
#pragma unroll
                for (int j = 0; j < 4; ++j) {
                    float f = ((const float*)&v[j])[i];
                    __bf16 h = (__bf16)f;
                    hv[j] = h;
                    lv[j] = (__bf16)(f - (float)h);
                }
                int row = s4 * 4 + i;
                *(v4bf*)&gxhi[row * 72 + cb * 4] = hv;
                *(v4bf*)&gxlo[row * 72 + cb * 4] = lv;
            }
            __syncthreads();
#pragma unroll
            for (int ks = 0; ks < 64; ks += 32) {
                v8bf bh[4], bl[4], ah[4], al[4];
#pragma unroll
                for (int nt = 0; nt < 4; ++nt) {
                    int off = (nt * 16 + lrow) * 72 + ks + lkg * 8;
                    bh[nt] = *(const v8bf*)&gxhi[off];
                    bl[nt] = *(const v8bf*)&gxlo[off];
                }
#pragma unroll
                for (int mt = 0; mt < 4; ++mt) {
                    int gi = (m_base + mt * 16 + lrow) * 1536 + c0 + ks + lkg * 8;
                    ah[mt] = *(const v8bf*)&Whi[gi];
                    al[mt] = *(const v8bf*)&Wlo[gi];
                }
#pragma unroll
                for (int mt = 0; mt < 4; ++mt)
#pragma unroll
                    for (int nt = 0; nt < 4; ++nt) {
                        acc[mt][nt] = __builtin_amdgcn_mfma_f32_16x16x32_bf16(
                            ah[mt], bh[nt], acc[mt][nt], 0, 0, 0);
                        acc[mt][nt] = __builtin_amdgcn_mfma_f32_16x16x32_bf16(
                            ah[mt], bl[nt], acc[mt][nt], 0, 0, 0);
                        acc[mt][nt] = __builtin_amdgcn_mfma_f32_16x16x32_bf16(
                            al[mt], bh[nt], acc[mt][nt], 0, 0, 0);
                    }
            }
        }
#pragma unroll
        for (int mt = 0; mt < 4; ++mt) {
#pragma unroll
            for (int r = 0; r < 4; ++r) {
                int m = m_base + mt * 16 + lkg * 4 + r;
                float bias = redu_b[m];
#pragma unroll
                for (int nt = 0; nt < 4; ++nt) {
                    int s = nt * 16 + lrow;
                    xt[(n * 512 + m) * 64 + s] = acc[mt][nt][r] + bias;
                }
            }
        }
        return;
    }

    // ================= recurrence path (R11, unchanged) =================
    const int b = blockIdx.x;
    const int lane = tid & 63;
    const int wave = tid >> 6;            // 0..3
    const int mt = wave;
    const int l15 = lane & 15, kg = lane >> 4, kg8 = kg * 8;
    const __bf16* Wp = (const __bf16*)ws + WPB;
    const __bf16* Wattx = (const __bf16*)ws + WATTX_BF16;
    const float* wxpb = ws + WXPB_OFF;
    float* hsg = ws + HS_OFF;
    float* asg = ws + ASUM_OFF;

    for (int i = tid; i < 4096; i += 256) h_s[i] = 0.f;

    // ---- one-time preamble: attv[tp] = conv3x3(wxpb[b*8+tp], att_x) on MFMA
    for (int tp = 0; tp < 8; ++tp) {
        const float* src = wxpb + (b * 8 + tp) * 4096;
        for (int i = tid; i < 4096; i += 256) {
            int k = i >> 6, s = i & 63;
            tA[s * 72 + k] = (__bf16)src[i];
        }
        __syncthreads();
        v4f av[4];
        conv_mfma(Wattx, tA, l15, kg8, mt, av);
#pragma unroll
        for (int i2 = 0; i2 < 4; ++i2)
#pragma unroll
            for (int r = 0; r < 4; ++r)
                attv_s[tp * 4096 + (mt * 16 + kg * 4 + r) * 64 + i2 * 16 + l15] =
                    (_Float16)av[i2][r];
        __syncthreads();
    }

    float abvr[2];
#pragma unroll
    for (int rep = 0; rep < 2; ++rep) abvr[rep] = att_b[(tid + rep * 256) >> 3];
    float sb4[4];
#pragma unroll
    for (int r = 0; r < 4; ++r) sb4[r] = share_b[mt * 16 + kg * 4 + r];

    for (int t = 0; t < 8; ++t) {
        // ---- tA = T(h)
#pragma unroll
        for (int rep = 0; rep < 2; ++rep) {
            int s = tid & 63, g = (tid >> 6) + rep * 4;
#pragma unroll
            for (int q4 = 0; q4 < 2; ++q4) {
                v4bf hv;
#pragma unroll
                for (int q = 0; q < 4; ++q) hv[q] = (__bf16)h_s[(g * 8 + q4 * 4 + q) * 64 + s];
                *(v4bf*)&tA[s * 72 + g * 8 + q4 * 4] = hv;
            }
        }
        __syncthreads();
        // ---- fused ah/Uz/Ur convs: ah -> cA; az, ar stay in registers
        v4f az[4], ar[4];
        {
            v4f a[4];
            conv_mfma3(Wp, Wp + 2u * 73728u, Wp + 3u * 73728u, tA,
                       l15, kg8, mt, a, az, ar);
#pragma unroll
            for (int i = 0; i < 4; ++i)
#pragma unroll
                for (int r = 0; r < 4; ++r)
                    cA[(mt * 16 + kg * 4 + r) * 65 + i * 16 + l15] = a[i][r];
        }
        __syncthreads();
        // ---- e = relu(attv+ah); mean/max over s -> em/ex
#pragma unroll
        for (int rep = 0; rep < 2; ++rep) {
            int vt = tid + rep * 256;
            int kk = vt >> 3, yy = vt & 7;
            float ah8[8];
            const float* cr = &cA[kk * 65 + yy * 8];
#pragma unroll
            for (int xx = 0; xx < 8; ++xx) ah8[xx] = cr[xx] + abvr[rep];
            for (int tp = 0; tp < 8; ++tp) {
                v8h va = *(const v8h*)&attv_s[tp * 4096 + kk * 64 + yy * 8];
                float s_ = 0.f, m_ = 0.f;
#pragma unroll
                for (int xx = 0; xx < 8; ++xx) {
                    float v = fmaxf((float)va[xx] + ah8[xx], 0.f);
                    s_ += v;
                    m_ = fmaxf(m_, v);
                }
                s_ += __shfl_down(s_, 4, 8);
                s_ += __shfl_down(s_, 2, 8);
                s_ += __shfl_down(s_, 1, 8);
                m_ = fmaxf(m_, __shfl_down(m_, 4, 8));
                m_ = fmaxf(m_, __shfl_down(m_, 2, 8));
                m_ = fmaxf(m_, __shfl_down(m_, 1, 8));
                if (yy == 0) {
                    misc[tp * 64 + kk] = s_ * (1.f / 64.f);
                    misc[512 + tp * 64 + kk] = m_;
                }
            }
        }
        __syncthreads();
        // ---- fc1: 64 outputs x 4 partials; 4-way acc split
        {
            int i2 = tid >> 2, part = tid & 3;
            int i = i2 & 31;
            const float* src = misc + ((i2 < 32) ? 0 : 512);
            const float* wrow = fc1_w + i * 512 + part * 128;
            const float* s2 = src + part * 128;
            float pa[4] = {0.f, 0.f, 0.f, 0.f};
#pragma unroll
            for (int c4 = 0; c4 < 32; ++c4) {
                float4 wv = *(const float4*)&wrow[c4 * 4];
                float4 sv = *(const float4*)&s2[c4 * 4];
                float* pp = &pa[c4 & 3];
                *pp = fmaf(wv.x, sv.x, *pp);
                *pp = fmaf(wv.y, sv.y, *pp);
                *pp = fmaf(wv.z, sv.z, *pp);
                *pp = fmaf(wv.w, sv.w, *pp);
            }
            float p = (pa[0] + pa[1]) + (pa[2] + pa[3]);
            p += __shfl_down(p, 2, 4);
            p += __shfl_down(p, 1, 4);
            if (part == 0) misc[1024 + i2] = fmaxf(p, 0.f);
        }
        __syncthreads();
        // ---- fc2 + tanh + exp -> exs at misc[0..511]
#pragma unroll
        for (int rep = 0; rep < 2; ++rep) {
            int vt = tid + rep * 256;
            const float* w2 = fc2_w + vt * 32;
            float gm = 0.f, gx = 0.f;
#pragma unroll
            for (int i4 = 0; i4 < 8; ++i4) {
                float4 wv = *(const float4*)&w2[i4 * 4];
                gm = fmaf(wv.x, misc[1024 + i4 * 4 + 0], gm);
                gm = fmaf(wv.y, misc[1024 + i4 * 4 + 1], gm);
                gm = fmaf(wv.z, misc[1024 + i4 * 4 + 2], gm);
                gm = fmaf(wv.w, misc[1024 + i4 * 4 + 3], gm);
                gx = fmaf(wv.x, misc[1056 + i4 * 4 + 0], gx);
                gx = fmaf(wv.y, misc[1056 + i4 * 4 + 1], gx);
                gx = fmaf(wv.z, misc[1056 + i4 * 4 + 2], gx);
                gx = fmaf(wv.w, misc[1056 + i4 * 4 + 3], gx);
            }
            misc[vt] = expf(tanhf(gm + gx));
        }
        __syncthreads();
        // ---- softmax over T -> als at misc[512..1023]
#pragma unroll
        for (int rep = 0; rep < 2; ++rep) {
            int vt = tid + rep * 256;
            int k6 = vt & 63;
            float den = 0.f;
#pragma unroll
            for (int tp = 0; tp < 8; ++tp) den += misc[tp * 64 + k6];
            den += (den == 0.f) ? 1.f : 0.f;
            misc[512 + vt] = misc[vt] / den;
        }
        __syncthreads();
        // ---- wxtp: read wxpb (L2-resident); then tA = T(wxtp)
#pragma unroll
        for (int rep = 0; rep < 2; ++rep) {
            int vt = tid + rep * 256;
            int kk = vt >> 3, yy = vt & 7;
            float wx8[8];
#pragma unroll
            for (int xx = 0; xx < 8; ++xx) wx8[xx] = 0.f;
            const float* src0 = wxpb + b * 32768 + kk * 64 + yy * 8;
#pragma unroll
            for (int tp = 0; tp < 8; ++tp) {
                float al = misc[512 + tp * 64 + kk];
                float4 v0 = *(const float4*)&src0[tp * 4096];
                float4 v1 = *(const float4*)&src0[tp * 4096 + 4];
                float v[8] = {v0.x, v0.y, v0.z, v0.w, v1.x, v1.y, v1.z, v1.w};
#pragma unroll
                for (int xx = 0; xx < 8; ++xx) wx8[xx] = fmaf(al, v[xx], wx8[xx]);
            }
#pragma unroll
            for (int xx = 0; xx < 8; ++xx) tA[(yy * 8 + xx) * 72 + kk] = (__bf16)wx8[xx];
        }
        __syncthreads();
        // ---- share conv
        v4f ash[4];
        conv_mfma(Wp + 1u * 73728u, tA, l15, kg8, mt, ash);
        // ---- gates (frag domain); rh -> cB
        float zf[4][4], wof[4][4];
#pragma unroll
        for (int i = 0; i < 4; ++i)
#pragma unroll
            for (int r = 0; r < 4; ++r) {
                int ko = mt * 16 + kg * 4 + r;
                int s = i * 16 + l15;
                float wo = ash[i][r] + sb4[r];
                float z = 1.f / (1.f + expf(-(wo + az[i][r])));
                float rr = 1.f / (1.f + expf(-(wo + ar[i][r])));
                cB[ko * 65 + s] = rr * h_s[ko * 64 + s];
                zf[i][r] = z;
                wof[i][r] = wo;
            }
        __syncthreads();
        // ---- tA = T(rh)
#pragma unroll
        for (int rep = 0; rep < 2; ++rep) {
            int s = tid & 63, g = (tid >> 6) + rep * 4;
#pragma unroll
            for (int q4 = 0; q4 < 2; ++q4) {
                v4bf hv;
#pragma unroll
                for (int q = 0; q < 4; ++q) hv[q] = (__bf16)cB[(g * 8 + q4 * 4 + q) * 65 + s];
                *(v4bf*)&tA[s * 72 + g * 8 + q4 * 4] = hv;
            }
        }
        __syncthreads();
        // ---- Uh conv + final update
        {
            v4f ach[4];
            conv_mfma(Wp + 4u * 73728u, tA, l15, kg8, mt, ach);
#pragma unroll
            for (int r = 0; r < 4; ++r) {
                int ko = mt * 16 + kg * 4 + r;
                float rsum = 0.f;
#pragma unroll
                for (int i = 0; i < 4; ++i) {
                    int s = i * 16 + l15;
                    float hh = tanhf(wof[i][r] + ach[i][r]);
                    float hold = h_s[ko * 64 + s];
                    float hn = (1.f - zf[i][r]) * hh + zf[i][r] * hold;
                    h_s[ko * 64 + s] = hn;
                    hsg[((t * 32 + b) * 64 + ko) * 64 + s] = hn;
                    rsum += hn;
                }
                rsum += __shfl_xor(rsum, 8, 16);
                rsum += __shfl_xor(rsum, 4, 16);
                rsum += __shfl_xor(rsum, 2, 16);
                rsum += __shfl_xor(rsum, 1, 16);
                if (l15 == 0) misc[1024 + ko] = rsum;
            }
        }
        __syncthreads();
        if (tid < 64) asg[b * 512 + t * 64 + tid] = misc[1024 + tid];
        __syncthreads();
    }
}

// ---------------------------------------------------------------------------
// VLAD: V[b,k,d] = sum_{t,hw} hs*xt - (sum_t asum)*centers. grid (8,32), 256 thr
__global__ __launch_bounds__(256) void k_vlad(const float* __restrict__ centers,
                                              const float* __restrict__ ws,
                                              float* __restrict__ out) {
    __shared__ float As[16 * 68];
    __shared__ float Bs[16 * 68];
    const int b = blockIdx.y;
    const int d0 = blockIdx.x * 64;
    const int tid = threadIdx.x;
    const int kq = tid & 15, dq = tid >> 4;
    const int lk = tid >> 2, q = tid & 3;
    const float* hs = ws + HS_OFF;
    const float* xt = ws + XT_OFF;
    float acc[4][4];
#pragma unroll
    for (int i = 0; i < 4; ++i)
#pragma unroll
        for (int j = 0; j < 4; ++j) acc[i][j] = 0.f;

    for (int rc = 0; rc < 512; rc += 16) {
        int t = rc >> 6, hw0 = rc & 63;
        float4 va = *(const float4*)&hs[((t * 32 + b) * 64 + lk) * 64 + hw0 + q * 4];
        float4 vb = *(const float4*)&xt[(b * 8 + t) * 32768 + (d0 + lk) * 64 + hw0 + q * 4];
        __syncthreads();
        As[(q * 4 + 0) * 68 + lk] = va.x;
        As[(q * 4 + 1) * 68 + lk] = va.y;
        As[(q * 4 + 2) * 68 + lk] = va.z;
        As[(q * 4 + 3) * 68 + lk] = va.w;
        Bs[(q * 4 + 0) * 68 + lk] = vb.x;
        Bs[(q * 4 + 1) * 68 + lk] = vb.y;
        Bs[(q * 4 + 2) * 68 + lk] = vb.z;
        Bs[(q * 4 + 3) * 68 + lk] = vb.w;
        __syncthreads();
#pragma unroll
        for (int cc = 0; cc < 16; ++cc) {
            float4 a = *(const float4*)&As[cc * 68 + kq * 4];
            float4 bb = *(const float4*)&Bs[cc * 68 + dq * 4];
            float av[4] = {a.x, a.y, a.z, a.w};
            float bv[4] = {bb.x, bb.y, bb.z, bb.w};
#pragma unroll
            for (int i = 0; i < 4; ++i)
#pragma unroll
                for (int j = 0; j < 4; ++j)
                    acc[i][j] = fmaf(av[i], bv[j], acc[i][j]);
        }
    }
    const float* asum = ws + ASUM_OFF;
#pragma unroll
    for (int i = 0; i < 4; ++i) {
        int k = kq * 4 + i;
        float at = 0.f;
#pragma unroll
        for (int tp = 0; tp < 8; ++tp) at += asum[b * 512 + tp * 64 + k];
        float4 cen = *(const float4*)&centers[k * 512 + d0 + dq * 4];
        float4 o = {acc[i][0] - at * cen.x, acc[i][1] - at * cen.y,
                    acc[i][2] - at * cen.z, acc[i][3] - at * cen.w};
        *(float4*)&out[b * 32768 + k * 512 + d0 + dq * 4] = o;
    }
}

// ---------------------------------------------------------------------------
__global__ __launch_bounds__(64) void k_norm1(float* __restrict__ out) {
    const int b = blockIdx.x >> 6, k = blockIdx.x & 63;
    float* p = out + b * 32768 + k * 512;
    const int tid = threadIdx.x;
    float v[8];
    float ss = 0.f;
#pragma unroll
    for (int i = 0; i < 8; ++i) {
        v[i] = p[tid + i * 64];
        ss = fmaf(v[i], v[i], ss);
    }
#pragma unroll
    for (int off = 32; off > 0; off >>= 1) ss += __shfl_down(ss, off, 64);
    ss = __shfl(ss, 0, 64);
    float sc = 1.f / fmaxf(sqrtf(ss), 1e-12f);
#pragma unroll
    for (int i = 0; i < 8; ++i) p[tid + i * 64] = v[i] * sc;
}

__global__ __launch_bounds__(256) void k_norm2(float* __restrict__ out) {
    __shared__ float red[4];
    __shared__ float stot;
    const int b = blockIdx.x;
    const int tid = threadIdx.x;
    float* p = out + b * 32768;
    float ss = 0.f;
    for (int i = 0; i < 32; ++i) {
        float4 v = *(const float4*)&p[tid * 4 + i * 1024];
        ss += v.x * v.x + v.y * v.y + v.z * v.z + v.w * v.w;
    }
#pragma unroll
    for (int off = 32; off > 0; off >>= 1) ss += __shfl_down(ss, off, 64);
    if ((tid & 63) == 0) red[tid >> 6] = ss;
    __syncthreads();
    if (tid == 0) stot = 1.f / fmaxf(sqrtf(red[0] + red[1] + red[2] + red[3]), 1e-12f);
    __syncthreads();
    float sc = stot;
    for (int i = 0; i < 32; ++i) {
        float4 v = *(const float4*)&p[tid * 4 + i * 1024];
        v.x *= sc; v.y *= sc; v.z *= sc; v.w *= sc;
        *(float4*)&p[tid * 4 + i * 1024] = v;
    }
}

// ---------------------------------------------------------------------------
extern "C" void kernel_launch(void* const* d_in, const int* in_sizes, int n_in,
                              void* d_out, int out_size, void* d_ws, size_t ws_size,
                              hipStream_t stream) {
    const float* x       = (const float*)d_in[0];
    const float* redu_w  = (const float*)d_in[1];
    const float* redu_b  = (const float*)d_in[2];
    const float* w_x     = (const float*)d_in[3];
    const float* att_x   = (const float*)d_in[4];
    const float* att_h_w = (const float*)d_in[5];
    const float* att_b   = (const float*)d_in[6];
    const float* share_w = (const float*)d_in[7];
    const float* share_b = (const float*)d_in[8];
    const float* U_r     = (const float*)d_in[9];
    const float* U_z     = (const float*)d_in[10];
    const float* U_h     = (const float*)d_in[11];
    const float* centers = (const float*)d_in[12];
    const float* fc1_w   = (const float*)d_in[13];
    const float* fc2_w   = (const float*)d_in[14];
    float* ws = (float*)d_ws;
    float* out = (float*)d_out;

    k_prep<<<dim3(3072), dim3(256), 0, stream>>>(redu_w, ws);
    k_prep_w<<<dim3(864), dim3(256), 0, stream>>>(att_h_w, share_w, U_z, U_r, U_h,
                                                  att_x, ws);
    k_w2<<<dim3(64), dim3(256), 0, stream>>>(w_x, redu_w, redu_b, ws);
    k_wxpb_direct<<<dim3(256), dim3(256), 0, stream>>>(x, ws);
    k_fused<<<dim3(544), dim3(256), 0, stream>>>(att_b, share_b, fc1_w, fc2_w,
                                                 x, redu_b, ws);
    k_vlad<<<dim3(8, 32), dim3(256), 0, stream>>>(centers, ws, out);
    k_norm1<<<dim3(2048), dim3(64), 0, stream>>>(out);
    k_norm2<<<dim3(32), dim3(256), 0, stream>>>(out);
}

// Round 13
// 704.628 us; speedup vs baseline: 1.0078x; 1.0078x over previous
//
#include <hip/hip_runtime.h>
#include <math.h>

// Problem constants
#define T_   8
#define K_   64
#define D_   512
#define CIN_ 1536
#define B_   32
#define S_   64    // H*W = 8*8
#define NT_  256   // B*T

// Workspace layout (float offsets)
#define WLO_BF16  786432u     // bf16-element offset of Wlo within bf16 view
#define XT_OFF    819200u     // [256][512][64]; also scratch for wxpb partials
#define WXPB_OFF  9207808u    // [256][64][64]
#define ATTV_OFF  10256384u   // region reused: att_x pack, W2 pack, b2
#define HS_OFF    11436032u   // [8][32][64][64]
#define ASUM_OFF  13041664u   // [32][8][64]
// conv-weight pack (bf16 elements): 5 weights x (hi 36864 + lo 36864),
// layout per weight: [dydx(9)][o(64)][i(64)]. Only hi halves are read (R4).
// Slots: 0=att_h_w 1=share_w 2=U_z 3=U_r 4=U_h.
#define WPB       25034752u
// ATTV-region tenants (all inside float span 10256384..11436032):
#define WATTX_BF16 20512768u  // att_x hi pack  (36864 bf16)
#define W2HI_BF16  20549632u  // W2 hi  [64][1536] bf16
#define W2LO_BF16  20647936u  // W2 lo  [64][1536] bf16 (ends 20746240 < 22872064)
#define B2_OFF     11435968u  // b2 [64] floats, abuts HS_OFF exactly

typedef __bf16 v8bf __attribute__((ext_vector_type(8)));
typedef __bf16 v4bf __attribute__((ext_vector_type(4)));
typedef float  v4f  __attribute__((ext_vector_type(4)));
typedef _Float16 v4h __attribute__((ext_vector_type(4)));
typedef _Float16 v8h __attribute__((ext_vector_type(8)));

// ---------------------------------------------------------------------------
// prep: split redu_w -> bf16 hi/lo
__global__ __launch_bounds__(256) void k_prep(const float* __restrict__ redu_w,
                                              float* __restrict__ ws) {
    unsigned idx = blockIdx.x * 256u + threadIdx.x;
    if (idx < 786432u) {
        float f = redu_w[idx];
        __bf16 h = (__bf16)f;
        __bf16 l = (__bf16)(f - (float)h);
        __bf16* wb = (__bf16*)ws;
        wb[idx] = h;
        wb[WLO_BF16 + idx] = l;
    }
}

// ---------------------------------------------------------------------------
// prep conv weights: [o][i][ky][kx] fp32 -> bf16 hi/lo [dydx][o][i].
// Slots 0..4 as in R8; slot 5 (att_x) hi-only into WATTX (R10).
__global__ __launch_bounds__(256) void k_prep_w(const float* __restrict__ w0,
                                                const float* __restrict__ w1,
                                                const float* __restrict__ w2,
                                                const float* __restrict__ w3,
                                                const float* __restrict__ w4,
                                                const float* __restrict__ w5,
                                                float* __restrict__ ws) {
    unsigned idx = blockIdx.x * 256u + threadIdx.x;
    if (idx >= 221184u) return;
    unsigned w = idx / 36864u, r = idx % 36864u;
    const float* src = (w == 0) ? w0 : (w == 1) ? w1 : (w == 2) ? w2
                     : (w == 3) ? w3 : (w == 4) ? w4 : w5;
    float f = src[r];
    __bf16 h = (__bf16)f;
    __bf16 l = (__bf16)(f - (float)h);
    unsigned o = r / 576u, rem = r % 576u, ii = rem / 9u, dydx = rem % 9u;
    __bf16* wb = (__bf16*)ws;
    if (w < 5u) {
        unsigned dst = WPB + w * 73728u + (dydx * 64u + o) * 64u + ii;
        wb[dst] = h;
        wb[dst + 36864u] = l;
    } else {
        wb[WATTX_BF16 + (dydx * 64u + o) * 64u + ii] = h;   // hi only
    }
}

// ---------------------------------------------------------------------------
// W2 = w_x @ redu_w (64x1536) -> bf16 hi/lo; b2 = w_x @ redu_b.
__global__ __launch_bounds__(256) void k_w2(const float* __restrict__ w_x,
                                            const float* __restrict__ redu_w,
                                            const float* __restrict__ redu_b,
                                            float* __restrict__ ws) {
    __shared__ float wrow[512];
    __shared__ float red[256];
    const int k = blockIdx.x;
    const int tid = threadIdx.x;
    wrow[tid] = w_x[k * 512 + tid];
    wrow[tid + 256] = w_x[k * 512 + tid + 256];
    __syncthreads();
    float acc[6] = {0.f, 0.f, 0.f, 0.f, 0.f, 0.f};
    for (int d = 0; d < 512; ++d) {
        float w = wrow[d];
        const float* rr = &redu_w[d * 1536 + tid];
#pragma unroll
        for (int j = 0; j < 6; ++j) acc[j] = fmaf(w, rr[j * 256], acc[j]);
    }
    __bf16* wb = (__bf16*)ws;
#pragma unroll
    for (int j = 0; j < 6; ++j) {
        int c = tid + j * 256;
        __bf16 h = (__bf16)acc[j];
        __bf16 l = (__bf16)(acc[j] - (float)h);
        wb[W2HI_BF16 + k * 1536 + c] = h;
        wb[W2LO_BF16 + k * 1536 + c] = l;
    }
    float p = wrow[tid] * redu_b[tid] + wrow[tid + 256] * redu_b[tid + 256];
    red[tid] = p;
    __syncthreads();
    for (int off = 128; off > 0; off >>= 1) {
        if (tid < off) red[tid] += red[tid + off];
        __syncthreads();
    }
    if (tid == 0) ws[B2_OFF + k] = red[0];
}

// ---------------------------------------------------------------------------
// R13: K-split wxpb partials. Grid (4, 256): blockIdx.y = n, blockIdx.x = K
// chunk (384 of 1536). 1024 blocks = 4 queued blocks/CU -> the serial 6-chunk
// staging chain per block is hidden by block-level parallelism (the R12
// monolithic version was 256 blocks x 24 serial chunks = ~150 us of exposed
// latency). Partials (no bias) go fp32 into the XT region — free until
// k_fused's gemm writes xt, which launches only after k_wxpb_red consumed it.
__global__ __launch_bounds__(256) void k_wxpb_part(const float* __restrict__ x,
                                                   float* __restrict__ ws) {
    __shared__ __bf16 xhi_s[64 * 72];
    __shared__ __bf16 xlo_s[64 * 72];
    const __bf16* __restrict__ W2h = (const __bf16*)ws + W2HI_BF16;
    const __bf16* __restrict__ W2l = (const __bf16*)ws + W2LO_BF16;
    const int n = blockIdx.y, ks4 = blockIdx.x;
    float* scratch = ws + XT_OFF + (n * 4 + ks4) * 4096;
    const int tid = threadIdx.x;
    const int wave = tid >> 6, lane = tid & 63;
    const int lrow = lane & 15, lkg = lane >> 4;
    const float* __restrict__ xn = x + n * 98304;
    const int s4 = tid & 15, cb = tid >> 4;

    v4f acc[4];
#pragma unroll
    for (int nt = 0; nt < 4; ++nt) acc[nt] = (v4f){0.f, 0.f, 0.f, 0.f};

    const int cbeg = ks4 * 384;
    for (int c0 = cbeg; c0 < cbeg + 384; c0 += 64) {
        float4 v[4];
#pragma unroll
        for (int j = 0; j < 4; ++j)
            v[j] = *(const float4*)&xn[(c0 + cb * 4 + j) * 64 + s4 * 4];
        __syncthreads();
#pragma unroll
        for (int i = 0; i < 4; ++i) {
            v4bf hv, lv;
#pragma unroll
            for (int j = 0; j < 4; ++j) {
                float f = ((const float*)&v[j])[i];
                __bf16 h = (__bf16)f;
                hv[j] = h;
                lv[j] = (__bf16)(f - (float)h);
            }
            int row = s4 * 4 + i;
            *(v4bf*)&xhi_s[row * 72 + cb * 4] = hv;
            *(v4bf*)&xlo_s[row * 72 + cb * 4] = lv;
        }
        __syncthreads();
#pragma unroll
        for (int ks = 0; ks < 64; ks += 32) {
            v8bf bh[4], bl[4];
#pragma unroll
            for (int nt = 0; nt < 4; ++nt) {
                int off = (nt * 16 + lrow) * 72 + ks + lkg * 8;
                bh[nt] = *(const v8bf*)&xhi_s[off];
                bl[nt] = *(const v8bf*)&xlo_s[off];
            }
            int gi = (wave * 16 + lrow) * 1536 + c0 + ks + lkg * 8;
            v8bf ah = *(const v8bf*)&W2h[gi];
            v8bf al = *(const v8bf*)&W2l[gi];
#pragma unroll
            for (int nt = 0; nt < 4; ++nt) {
                acc[nt] = __builtin_amdgcn_mfma_f32_16x16x32_bf16(ah, bh[nt], acc[nt], 0, 0, 0);
                acc[nt] = __builtin_amdgcn_mfma_f32_16x16x32_bf16(ah, bl[nt], acc[nt], 0, 0, 0);
                acc[nt] = __builtin_amdgcn_mfma_f32_16x16x32_bf16(al, bh[nt], acc[nt], 0, 0, 0);
            }
        }
    }
#pragma unroll
    for (int r = 0; r < 4; ++r) {
        int m = wave * 16 + lkg * 4 + r;
#pragma unroll
        for (int nt = 0; nt < 4; ++nt)
            scratch[m * 64 + nt * 16 + lrow] = acc[nt][r];
    }
}

// ---------------------------------------------------------------------------
// R13: reduce 4 K-partials + b2 -> wxpb. grid 256 (one per n), 256 threads.
__global__ __launch_bounds__(256) void k_wxpb_red(float* __restrict__ ws) {
    const int n = blockIdx.x, tid = threadIdx.x;
    const float* sc = ws + XT_OFF + n * 4 * 4096;
    const float* b2 = ws + B2_OFF;
    float* wxpb = ws + WXPB_OFF + n * 4096;
#pragma unroll
    for (int e = 0; e < 16; ++e) {
        int idx = tid + e * 256;
        int m = idx >> 6;
        float v = b2[m] + sc[idx] + sc[4096 + idx] + sc[8192 + idx] + sc[12288 + idx];
        wxpb[idx] = v;
    }
}

// ---------------------------------------------------------------------------
// R8 conv: 4 waves, each wave owns rows mt*16..+15, all 64 cols (acc[4]).
__device__ __forceinline__ void conv_mfma(const __bf16* __restrict__ Wh,
                                          const __bf16* tS,
                                          int l15, int kg8, int mt, v4f acc[4]) {
    v8bf vz;
#pragma unroll
    for (int q = 0; q < 8; ++q) vz[q] = (__bf16)0.f;
#pragma unroll
    for (int i = 0; i < 4; ++i) acc[i] = (v4f){0.f, 0.f, 0.f, 0.f};
    const int yb = l15 >> 3, xb = l15 & 7;
    v8bf wh[9][2];
#pragma unroll
    for (int p = 0; p < 9; ++p) {
        const int wrow = (p * 64 + mt * 16 + l15) * 64 + kg8;
#pragma unroll
        for (int kci = 0; kci < 2; ++kci)
            wh[p][kci] = *(const v8bf*)&Wh[wrow + kci * 32];
    }
#pragma unroll
    for (int dy = 0; dy < 3; ++dy)
#pragma unroll
        for (int dx = 0; dx < 3; ++dx) {
            const int x0 = xb + dx - 1;
            const bool okx = (unsigned)x0 < 8u;
#pragma unroll
            for (int i = 0; i < 4; ++i) {
                const int y0 = yb + dy - 1 + 2 * i;
                const bool ok = ((unsigned)y0 < 8u) & okx;
                const int s0 = ((y0 * 8 + x0) & 63) * 72 + kg8;
#pragma unroll
                for (int kci = 0; kci < 2; ++kci) {
                    v8bf b = ok ? *(const v8bf*)&tS[s0 + kci * 32] : vz;
                    acc[i] = __builtin_amdgcn_mfma_f32_16x16x32_bf16(
                        wh[dy * 3 + dx][kci], b, acc[i], 0, 0, 0);
                }
            }
        }
}

// Fused triple conv over the same tA (ah/Uz/Ur).
__device__ __forceinline__ void conv_mfma3(const __bf16* __restrict__ W0,
                                           const __bf16* __restrict__ W1,
                                           const __bf16* __restrict__ W2,
                                           const __bf16* tS,
                                           int l15, int kg8, int mt,
                                           v4f a0[4], v4f a1[4], v4f a2[4]) {
    v8bf vz;
#pragma unroll
    for (int q = 0; q < 8; ++q) vz[q] = (__bf16)0.f;
#pragma unroll
    for (int i = 0; i < 4; ++i) {
        a0[i] = (v4f){0.f, 0.f, 0.f, 0.f};
        a1[i] = (v4f){0.f, 0.f, 0.f, 0.f};
        a2[i] = (v4f){0.f, 0.f, 0.f, 0.f};
    }
    const int yb = l15 >> 3, xb = l15 & 7;
#pragma unroll
    for (int dy = 0; dy < 3; ++dy) {
        v8bf w0[3][2], w1[3][2], w2[3][2];
#pragma unroll
        for (int dx = 0; dx < 3; ++dx) {
            const int wrow = ((dy * 3 + dx) * 64 + mt * 16 + l15) * 64 + kg8;
#pragma unroll
            for (int kci = 0; kci < 2; ++kci) {
                w0[dx][kci] = *(const v8bf*)&W0[wrow + kci * 32];
                w1[dx][kci] = *(const v8bf*)&W1[wrow + kci * 32];
                w2[dx][kci] = *(const v8bf*)&W2[wrow + kci * 32];
            }
        }
#pragma unroll
        for (int dx = 0; dx < 3; ++dx) {
            const int x0 = xb + dx - 1;
            const bool okx = (unsigned)x0 < 8u;
#pragma unroll
            for (int i = 0; i < 4; ++i) {
                const int y0 = yb + dy - 1 + 2 * i;
                const bool ok = ((unsigned)y0 < 8u) & okx;
                const int s0 = ((y0 * 8 + x0) & 63) * 72 + kg8;
#pragma unroll
                for (int kci = 0; kci < 2; ++kci) {
                    v8bf b = ok ? *(const v8bf*)&tS[s0 + kci * 32] : vz;
                    a0[i] = __builtin_amdgcn_mfma_f32_16x16x32_bf16(w0[dx][kci], b, a0[i], 0, 0, 0);
                    a1[i] = __builtin_amdgcn_mfma_f32_16x16x32_bf16(w1[dx][kci], b, a1[i], 0, 0, 0);
                    a2[i] = __builtin_amdgcn_mfma_f32_16x16x32_bf16(w2[dx][kci], b, a2[i], 0, 0, 0);
                }
            }
        }
    }
}

// ---------------------------------------------------------------------------
// R12 fused kernel: grid 544, 256 threads.
//   blocks 0..31   : the R11 recurrence (reads wxpb, writes hsg/asg).
//   blocks 32..543 : the xt GEMM, concurrent on the idle CUs.
__global__ __launch_bounds__(256) void k_fused(const float* __restrict__ att_b,
                                               const float* __restrict__ share_b,
                                               const float* __restrict__ fc1_w,
                                               const float* __restrict__ fc2_w,
                                               const float* __restrict__ x,
                                               const float* __restrict__ redu_b,
                                               float* __restrict__ ws) {
    __shared__ float h_s[4096];                                   // h [k][s]
    __shared__ __attribute__((aligned(16))) __bf16 tA[64 * 72];   // T(in) [s][kp]
    __shared__ float cA[64 * 65];                                 // conv out / scratch
    __shared__ float cB[64 * 65];
    __shared__ float misc[1088];
    __shared__ __attribute__((aligned(16))) _Float16 attv_s[32768];  // [tp][k][s] fp16
    const int tid = threadIdx.x;

    if (blockIdx.x >= 32) {
        // ================= xt GEMM path =================
        const int gb = blockIdx.x - 32;
        const int n = gb >> 1;
        const int d0 = (gb & 1) * 256;
        const __bf16* __restrict__ Whi = (const __bf16*)ws;
        const __bf16* __restrict__ Wlo = ((const __bf16*)ws) + WLO_BF16;
        float* xt = ws + XT_OFF;
        const int wave = tid >> 6, lane = tid & 63;
        const int lrow = lane & 15, lkg = lane >> 4;
        const int m_base = d0 + wave * 64;
        const float* __restrict__ xn = x + n * 98304;
        const int s4 = tid & 15, cb = tid >> 4;
        __bf16* gxhi = (__bf16*)attv_s;        // alias: 2*4608 bf16 = 18.4 KB
        __bf16* gxlo = gxhi + 4608;

        v4f acc[4][4];
#pragma unroll
        for (int mt = 0; mt < 4; ++mt)
#pragma unroll
            for (int nt = 0; nt < 4; ++nt) acc[mt][nt] = (v4f){0.f, 0.f, 0.f, 0.f};

        for (int c0 = 0; c0 < 1536; c0 += 64) {
            float4 v[4];
#pragma unroll
            for (int j = 0; j < 4; ++j)
                v[j] = *(const float4*)&xn[(c0 + cb * 4 + j) * 64 + s4 * 4];
            __syncthreads();
#pragma unroll
            for (int i = 0; i < 4; ++i) {
                v4bf hv, lv;
#pragma unroll
                for (int j = 0; j < 4; ++j) {
                    float f = ((const float*)&v[j])[i];
                    __bf16 h = (__bf16)f;
                    hv[j] = h;
                    lv[j] = (__bf16)(f - (float)h);
                }
                int row = s4 * 4 + i;
                *(v4bf*)&gxhi[row * 72 + cb * 4] = hv;
                *(v4bf*)&gxlo[row * 72 + cb * 4] = lv;
            }
            __syncthreads();
#pragma unroll
            for (int ks = 0; ks < 64; ks += 32) {
                v8bf bh[4], bl[4], ah[4], al[4];
#pragma unroll
                for (int nt = 0; nt < 4; ++nt) {
                    int off = (nt * 16 + lrow) * 72 + ks + lkg * 8;
                    bh[nt] = *(const v8bf*)&gxhi[off];
                    bl[nt] = *(const v8bf*)&gxlo[off];
                }
#pragma unroll
                for (int mt = 0; mt < 4; ++mt) {
                    int gi = (m_base + mt * 16 + lrow) * 1536 + c0 + ks + lkg * 8;
                    ah[mt] = *(const v8bf*)&Whi[gi];
                    al[mt] = *(const v8bf*)&Wlo[gi];
                }
#pragma unroll
                for (int mt = 0; mt < 4; ++mt)
#pragma unroll
                    for (int nt = 0; nt < 4; ++nt) {
                        acc[mt][nt] = __builtin_amdgcn_mfma_f32_16x16x32_bf16(
                            ah[mt], bh[nt], acc[mt][nt], 0, 0, 0);
                        acc[mt][nt] = __builtin_amdgcn_mfma_f32_16x16x32_bf16(
                            ah[mt], bl[nt], acc[mt][nt], 0, 0, 0);
                        acc[mt][nt] = __builtin_amdgcn_mfma_f32_16x16x32_bf16(
                            al[mt], bh[nt], acc[mt][nt], 0, 0, 0);
                    }
            }
        }
#pragma unroll
        for (int mt = 0; mt < 4; ++mt) {
#pragma unroll
            for (int r = 0; r < 4; ++r) {
                int m = m_base + mt * 16 + lkg * 4 + r;
                float bias = redu_b[m];
#pragma unroll
                for (int nt = 0; nt < 4; ++nt) {
                    int s = nt * 16 + lrow;
                    xt[(n * 512 + m) * 64 + s] = acc[mt][nt][r] + bias;
                }
            }
        }
        return;
    }

    // ================= recurrence path (R11, unchanged) =================
    const int b = blockIdx.x;
    const int lane = tid & 63;
    const int wave = tid >> 6;            // 0..3
    const int mt = wave;
    const int l15 = lane & 15, kg = lane >> 4, kg8 = kg * 8;
    const __bf16* Wp = (const __bf16*)ws + WPB;
    const __bf16* Wattx = (const __bf16*)ws + WATTX_BF16;
    const float* wxpb = ws + WXPB_OFF;
    float* hsg = ws + HS_OFF;
    float* asg = ws + ASUM_OFF;

    for (int i = tid; i < 4096; i += 256) h_s[i] = 0.f;

    // ---- one-time preamble: attv[tp] = conv3x3(wxpb[b*8+tp], att_x) on MFMA
    for (int tp = 0; tp < 8; ++tp) {
        const float* src = wxpb + (b * 8 + tp) * 4096;
        for (int i = tid; i < 4096; i += 256) {
            int k = i >> 6, s = i & 63;
            tA[s * 72 + k] = (__bf16)src[i];
        }
        __syncthreads();
        v4f av[4];
        conv_mfma(Wattx, tA, l15, kg8, mt, av);
#pragma unroll
        for (int i2 = 0; i2 < 4; ++i2)
#pragma unroll
            for (int r = 0; r < 4; ++r)
                attv_s[tp * 4096 + (mt * 16 + kg * 4 + r) * 64 + i2 * 16 + l15] =
                    (_Float16)av[i2][r];
        __syncthreads();
    }

    float abvr[2];
#pragma unroll
    for (int rep = 0; rep < 2; ++rep) abvr[rep] = att_b[(tid + rep * 256) >> 3];
    float sb4[4];
#pragma unroll
    for (int r = 0; r < 4; ++r) sb4[r] = share_b[mt * 16 + kg * 4 + r];

    for (int t = 0; t < 8; ++t) {
        // ---- tA = T(h)
#pragma unroll
        for (int rep = 0; rep < 2; ++rep) {
            int s = tid & 63, g = (tid >> 6) + rep * 4;
#pragma unroll
            for (int q4 = 0; q4 < 2; ++q4) {
                v4bf hv;
#pragma unroll
                for (int q = 0; q < 4; ++q) hv[q] = (__bf16)h_s[(g * 8 + q4 * 4 + q) * 64 + s];
                *(v4bf*)&tA[s * 72 + g * 8 + q4 * 4] = hv;
            }
        }
        __syncthreads();
        // ---- fused ah/Uz/Ur convs: ah -> cA; az, ar stay in registers
        v4f az[4], ar[4];
        {
            v4f a[4];
            conv_mfma3(Wp, Wp + 2u * 73728u, Wp + 3u * 73728u, tA,
                       l15, kg8, mt, a, az, ar);
#pragma unroll
            for (int i = 0; i < 4; ++i)
#pragma unroll
                for (int r = 0; r < 4; ++r)
                    cA[(mt * 16 + kg * 4 + r) * 65 + i * 16 + l15] = a[i][r];
        }
        __syncthreads();
        // ---- e = relu(attv+ah); mean/max over s -> em/ex
#pragma unroll
        for (int rep = 0; rep < 2; ++rep) {
            int vt = tid + rep * 256;
            int kk = vt >> 3, yy = vt & 7;
            float ah8[8];
            const float* cr = &cA[kk * 65 + yy * 8];
#pragma unroll
            for (int xx = 0; xx < 8; ++xx) ah8[xx] = cr[xx] + abvr[rep];
            for (int tp = 0; tp < 8; ++tp) {
                v8h va = *(const v8h*)&attv_s[tp * 4096 + kk * 64 + yy * 8];
                float s_ = 0.f, m_ = 0.f;
#pragma unroll
                for (int xx = 0; xx < 8; ++xx) {
                    float v = fmaxf((float)va[xx] + ah8[xx], 0.f);
                    s_ += v;
                    m_ = fmaxf(m_, v);
                }
                s_ += __shfl_down(s_, 4, 8);
                s_ += __shfl_down(s_, 2, 8);
                s_ += __shfl_down(s_, 1, 8);
                m_ = fmaxf(m_, __shfl_down(m_, 4, 8));
                m_ = fmaxf(m_, __shfl_down(m_, 2, 8));
                m_ = fmaxf(m_, __shfl_down(m_, 1, 8));
                if (yy == 0) {
                    misc[tp * 64 + kk] = s_ * (1.f / 64.f);
                    misc[512 + tp * 64 + kk] = m_;
                }
            }
        }
        __syncthreads();
        // ---- fc1: 64 outputs x 4 partials; 4-way acc split
        {
            int i2 = tid >> 2, part = tid & 3;
            int i = i2 & 31;
            const float* src = misc + ((i2 < 32) ? 0 : 512);
            const float* wrow = fc1_w + i * 512 + part * 128;
            const float* s2 = src + part * 128;
            float pa[4] = {0.f, 0.f, 0.f, 0.f};
#pragma unroll
            for (int c4 = 0; c4 < 32; ++c4) {
                float4 wv = *(const float4*)&wrow[c4 * 4];
                float4 sv = *(const float4*)&s2[c4 * 4];
                float* pp = &pa[c4 & 3];
                *pp = fmaf(wv.x, sv.x, *pp);
                *pp = fmaf(wv.y, sv.y, *pp);
                *pp = fmaf(wv.z, sv.z, *pp);
                *pp = fmaf(wv.w, sv.w, *pp);
            }
            float p = (pa[0] + pa[1]) + (pa[2] + pa[3]);
            p += __shfl_down(p, 2, 4);
            p += __shfl_down(p, 1, 4);
            if (part == 0) misc[1024 + i2] = fmaxf(p, 0.f);
        }
        __syncthreads();
        // ---- fc2 + tanh + exp -> exs at misc[0..511]
#pragma unroll
        for (int rep = 0; rep < 2; ++rep) {
            int vt = tid + rep * 256;
            const float* w2 = fc2_w + vt * 32;
            float gm = 0.f, gx = 0.f;
#pragma unroll
            for (int i4 = 0; i4 < 8; ++i4) {
                float4 wv = *(const float4*)&w2[i4 * 4];
                gm = fmaf(wv.x, misc[1024 + i4 * 4 + 0], gm);
                gm = fmaf(wv.y, misc[1024 + i4 * 4 + 1], gm);
                gm = fmaf(wv.z, misc[1024 + i4 * 4 + 2], gm);
                gm = fmaf(wv.w, misc[1024 + i4 * 4 + 3], gm);
                gx = fmaf(wv.x, misc[1056 + i4 * 4 + 0], gx);
                gx = fmaf(wv.y, misc[1056 + i4 * 4 + 1], gx);
                gx = fmaf(wv.z, misc[1056 + i4 * 4 + 2], gx);
                gx = fmaf(wv.w, misc[1056 + i4 * 4 + 3], gx);
            }
            misc[vt] = expf(tanhf(gm + gx));
        }
        __syncthreads();
        // ---- softmax over T -> als at misc[512..1023]
#pragma unroll
        for (int rep = 0; rep < 2; ++rep) {
            int vt = tid + rep * 256;
            int k6 = vt & 63;
            float den = 0.f;
#pragma unroll
            for (int tp = 0; tp < 8; ++tp) den += misc[tp * 64 + k6];
            den += (den == 0.f) ? 1.f : 0.f;
            misc[512 + vt] = misc[vt] / den;
        }
        __syncthreads();
        // ---- wxtp: read wxpb (L2-resident); then tA = T(wxtp)
#pragma unroll
        for (int rep = 0; rep < 2; ++rep) {
            int vt = tid + rep * 256;
            int kk = vt >> 3, yy = vt & 7;
            float wx8[8];
#pragma unroll
            for (int xx = 0; xx < 8; ++xx) wx8[xx] = 0.f;
            const float* src0 = wxpb + b * 32768 + kk * 64 + yy * 8;
#pragma unroll
            for (int tp = 0; tp < 8; ++tp) {
                float al = misc[512 + tp * 64 + kk];
                float4 v0 = *(const float4*)&src0[tp * 4096];
                float4 v1 = *(const float4*)&src0[tp * 4096 + 4];
                float v[8] = {v0.x, v0.y, v0.z, v0.w, v1.x, v1.y, v1.z, v1.w};
#pragma unroll
                for (int xx = 0; xx < 8; ++xx) wx8[xx] = fmaf(al, v[xx], wx8[xx]);
            }
#pragma unroll
            for (int xx = 0; xx < 8; ++xx) tA[(yy * 8 + xx) * 72 + kk] = (__bf16)wx8[xx];
        }
        __syncthreads();
        // ---- share conv
        v4f ash[4];
        conv_mfma(Wp + 1u * 73728u, tA, l15, kg8, mt, ash);
        // ---- gates (frag domain); rh -> cB
        float zf[4][4], wof[4][4];
#pragma unroll
        for (int i = 0; i < 4; ++i)
#pragma unroll
            for (int r = 0; r < 4; ++r) {
                int ko = mt * 16 + kg * 4 + r;
                int s = i * 16 + l15;
                float wo = ash[i][r] + sb4[r];
                float z = 1.f / (1.f + expf(-(wo + az[i][r])));
                float rr = 1.f / (1.f + expf(-(wo + ar[i][r])));
                cB[ko * 65 + s] = rr * h_s[ko * 64 + s];
                zf[i][r] = z;
                wof[i][r] = wo;
            }
        __syncthreads();
        // ---- tA = T(rh)
#pragma unroll
        for (int rep = 0; rep < 2; ++rep) {
            int s = tid & 63, g = (tid >> 6) + rep * 4;
#pragma unroll
            for (int q4 = 0; q4 < 2; ++q4) {
                v4bf hv;
#pragma unroll
                for (int q = 0; q < 4; ++q) hv[q] = (__bf16)cB[(g * 8 + q4 * 4 + q) * 65 + s];
                *(v4bf*)&tA[s * 72 + g * 8 + q4 * 4] = hv;
            }
        }
        __syncthreads();
        // ---- Uh conv + final update
        {
            v4f ach[4];
            conv_mfma(Wp + 4u * 73728u, tA, l15, kg8, mt, ach);
#pragma unroll
            for (int r = 0; r < 4; ++r) {
                int ko = mt * 16 + kg * 4 + r;
                float rsum = 0.f;
#pragma unroll
                for (int i = 0; i < 4; ++i) {
                    int s = i * 16 + l15;
                    float hh = tanhf(wof[i][r] + ach[i][r]);
                    float hold = h_s[ko * 64 + s];
                    float hn = (1.f - zf[i][r]) * hh + zf[i][r] * hold;
                    h_s[ko * 64 + s] = hn;
                    hsg[((t * 32 + b) * 64 + ko) * 64 + s] = hn;
                    rsum += hn;
                }
                rsum += __shfl_xor(rsum, 8, 16);
                rsum += __shfl_xor(rsum, 4, 16);
                rsum += __shfl_xor(rsum, 2, 16);
                rsum += __shfl_xor(rsum, 1, 16);
                if (l15 == 0) misc[1024 + ko] = rsum;
            }
        }
        __syncthreads();
        if (tid < 64) asg[b * 512 + t * 64 + tid] = misc[1024 + tid];
        __syncthreads();
    }
}

// ---------------------------------------------------------------------------
// VLAD: V[b,k,d] = sum_{t,hw} hs*xt - (sum_t asum)*centers. grid (8,32), 256 thr
__global__ __launch_bounds__(256) void k_vlad(const float* __restrict__ centers,
                                              const float* __restrict__ ws,
                                              float* __restrict__ out) {
    __shared__ float As[16 * 68];
    __shared__ float Bs[16 * 68];
    const int b = blockIdx.y;
    const int d0 = blockIdx.x * 64;
    const int tid = threadIdx.x;
    const int kq = tid & 15, dq = tid >> 4;
    const int lk = tid >> 2, q = tid & 3;
    const float* hs = ws + HS_OFF;
    const float* xt = ws + XT_OFF;
    float acc[4][4];
#pragma unroll
    for (int i = 0; i < 4; ++i)
#pragma unroll
        for (int j = 0; j < 4; ++j) acc[i][j] = 0.f;

    for (int rc = 0; rc < 512; rc += 16) {
        int t = rc >> 6, hw0 = rc & 63;
        float4 va = *(const float4*)&hs[((t * 32 + b) * 64 + lk) * 64 + hw0 + q * 4];
        float4 vb = *(const float4*)&xt[(b * 8 + t) * 32768 + (d0 + lk) * 64 + hw0 + q * 4];
        __syncthreads();
        As[(q * 4 + 0) * 68 + lk] = va.x;
        As[(q * 4 + 1) * 68 + lk] = va.y;
        As[(q * 4 + 2) * 68 + lk] = va.z;
        As[(q * 4 + 3) * 68 + lk] = va.w;
        Bs[(q * 4 + 0) * 68 + lk] = vb.x;
        Bs[(q * 4 + 1) * 68 + lk] = vb.y;
        Bs[(q * 4 + 2) * 68 + lk] = vb.z;
        Bs[(q * 4 + 3) * 68 + lk] = vb.w;
        __syncthreads();
#pragma unroll
        for (int cc = 0; cc < 16; ++cc) {
            float4 a = *(const float4*)&As[cc * 68 + kq * 4];
            float4 bb = *(const float4*)&Bs[cc * 68 + dq * 4];
            float av[4] = {a.x, a.y, a.z, a.w};
            float bv[4] = {bb.x, bb.y, bb.z, bb.w};
#pragma unroll
            for (int i = 0; i < 4; ++i)
#pragma unroll
                for (int j = 0; j < 4; ++j)
                    acc[i][j] = fmaf(av[i], bv[j], acc[i][j]);
        }
    }
    const float* asum = ws + ASUM_OFF;
#pragma unroll
    for (int i = 0; i < 4; ++i) {
        int k = kq * 4 + i;
        float at = 0.f;
#pragma unroll
        for (int tp = 0; tp < 8; ++tp) at += asum[b * 512 + tp * 64 + k];
        float4 cen = *(const float4*)&centers[k * 512 + d0 + dq * 4];
        float4 o = {acc[i][0] - at * cen.x, acc[i][1] - at * cen.y,
                    acc[i][2] - at * cen.z, acc[i][3] - at * cen.w};
        *(float4*)&out[b * 32768 + k * 512 + d0 + dq * 4] = o;
    }
}

// ---------------------------------------------------------------------------
__global__ __launch_bounds__(64) void k_norm1(float* __restrict__ out) {
    const int b = blockIdx.x >> 6, k = blockIdx.x & 63;
    float* p = out + b * 32768 + k * 512;
    const int tid = threadIdx.x;
    float v[8];
    float ss = 0.f;
#pragma unroll
    for (int i = 0; i < 8; ++i) {
        v[i] = p[tid + i * 64];
        ss = fmaf(v[i], v[i], ss);
    }
#pragma unroll
    for (int off = 32; off > 0; off >>= 1) ss += __shfl_down(ss, off, 64);
    ss = __shfl(ss, 0, 64);
    float sc = 1.f / fmaxf(sqrtf(ss), 1e-12f);
#pragma unroll
    for (int i = 0; i < 8; ++i) p[tid + i * 64] = v[i] * sc;
}

__global__ __launch_bounds__(256) void k_norm2(float* __restrict__ out) {
    __shared__ float red[4];
    __shared__ float stot;
    const int b = blockIdx.x;
    const int tid = threadIdx.x;
    float* p = out + b * 32768;
    float ss = 0.f;
    for (int i = 0; i < 32; ++i) {
        float4 v = *(const float4*)&p[tid * 4 + i * 1024];
        ss += v.x * v.x + v.y * v.y + v.z * v.z + v.w * v.w;
    }
#pragma unroll
    for (int off = 32; off > 0; off >>= 1) ss += __shfl_down(ss, off, 64);
    if ((tid & 63) == 0) red[tid >> 6] = ss;
    __syncthreads();
    if (tid == 0) stot = 1.f / fmaxf(sqrtf(red[0] + red[1] + red[2] + red[3]), 1e-12f);
    __syncthreads();
    float sc = stot;
    for (int i = 0; i < 32; ++i) {
        float4 v = *(const float4*)&p[tid * 4 + i * 1024];
        v.x *= sc; v.y *= sc; v.z *= sc; v.w *= sc;
        *(float4*)&p[tid * 4 + i * 1024] = v;
    }
}

// ---------------------------------------------------------------------------
extern "C" void kernel_launch(void* const* d_in, const int* in_sizes, int n_in,
                              void* d_out, int out_size, void* d_ws, size_t ws_size,
                              hipStream_t stream) {
    const float* x       = (const float*)d_in[0];
    const float* redu_w  = (const float*)d_in[1];
    const float* redu_b  = (const float*)d_in[2];
    const float* w_x     = (const float*)d_in[3];
    const float* att_x   = (const float*)d_in[4];
    const float* att_h_w = (const float*)d_in[5];
    const float* att_b   = (const float*)d_in[6];
    const float* share_w = (const float*)d_in[7];
    const float* share_b = (const float*)d_in[8];
    const float* U_r     = (const float*)d_in[9];
    const float* U_z     = (const float*)d_in[10];
    const float* U_h     = (const float*)d_in[11];
    const float* centers = (const float*)d_in[12];
    const float* fc1_w   = (const float*)d_in[13];
    const float* fc2_w   = (const float*)d_in[14];
    float* ws = (float*)d_ws;
    float* out = (float*)d_out;

    k_prep<<<dim3(3072), dim3(256), 0, stream>>>(redu_w, ws);
    k_prep_w<<<dim3(864), dim3(256), 0, stream>>>(att_h_w, share_w, U_z, U_r, U_h,
                                                  att_x, ws);
    k_w2<<<dim3(64), dim3(256), 0, stream>>>(w_x, redu_w, redu_b, ws);
    k_wxpb_part<<<dim3(4, 256), dim3(256), 0, stream>>>(x, ws);
    k_wxpb_red<<<dim3(256), dim3(256), 0, stream>>>(ws);
    k_fused<<<dim3(544), dim3(256), 0, stream>>>(att_b, share_b, fc1_w, fc2_w,
                                                 x, redu_b, ws);
    k_vlad<<<dim3(8, 32), dim3(256), 0, stream>>>(centers, ws, out);
    k_norm1<<<dim3(2048), dim3(64), 0, stream>>>(out);
    k_norm2<<<dim3(32), dim3(256), 0, stream>>>(out);
}